// Round 4
// baseline (1841.795 us; speedup 1.0000x reference)
//
#include <hip/hip_runtime.h>

// GIN forward: bucket-binned aggregation (256-node buckets, LDS accumulator)
// + transformed-space linearity (y = h@wa; agg@wa = y_self + sum y_nbr).
// Pipeline: bin-hist -> scan -> bin-fill -> pre -> 3x(agg + MLP) + pool + head.
// fp32 throughout. N=100000, E=1200000, DIM=64, G=1000, IN=11.

#define BN_EPS 1e-5f
#define NBUCK 512          // power-of-2 >= ceil(N/256)
#define NBLK  256          // binning blocks

// ---------------- binning: per-block histogram (bucket-major layout) -------
__global__ __launch_bounds__(256)
void bin_hist_kernel(const int* __restrict__ dst, int* __restrict__ ghist,
                     int E, int chunk) {
    __shared__ int h[NBUCK];
    const int tid = threadIdx.x, blk = blockIdx.x;
    for (int u = tid; u < NBUCK; u += 256) h[u] = 0;
    __syncthreads();
    const int e0 = blk * chunk, e1 = min(E, e0 + chunk);
    for (int e = e0 + tid; e < e1; e += 256)
        atomicAdd(&h[dst[e] >> 8], 1);
    __syncthreads();
    for (int u = tid; u < NBUCK; u += 256)
        ghist[u * NBLK + blk] = h[u];     // bucket-major
}

// ---------------- generic hierarchical exclusive scan ----------------------
__global__ __launch_bounds__(256)
void scan_block_g(int* __restrict__ a, int* __restrict__ bsum, int n) {
    __shared__ int s[256];
    int i = blockIdx.x * 256 + threadIdx.x;
    int v = (i < n) ? a[i] : 0;
    s[threadIdx.x] = v;
    __syncthreads();
    for (int off = 1; off < 256; off <<= 1) {
        int t = (threadIdx.x >= off) ? s[threadIdx.x - off] : 0;
        __syncthreads();
        s[threadIdx.x] += t;
        __syncthreads();
    }
    if (i < n) a[i] = s[threadIdx.x] - v;
    if (threadIdx.x == 255) bsum[blockIdx.x] = s[255];
}

__global__ __launch_bounds__(512)
void scan_top_kernel(int* bsum, int nb) {
    __shared__ int s[512];
    int v = (threadIdx.x < nb) ? bsum[threadIdx.x] : 0;
    s[threadIdx.x] = v;
    __syncthreads();
    for (int off = 1; off < 512; off <<= 1) {
        int t = (threadIdx.x >= off) ? s[threadIdx.x - off] : 0;
        __syncthreads();
        s[threadIdx.x] += t;
        __syncthreads();
    }
    if (threadIdx.x < nb) bsum[threadIdx.x] = s[threadIdx.x] - v;
}

__global__ __launch_bounds__(256)
void scan_add_g(int* __restrict__ a, const int* __restrict__ bsum, int n) {
    int i = blockIdx.x * 256 + threadIdx.x;
    if (i < n) a[i] += bsum[blockIdx.x];
}

// ---------------- bin fill: block-local LDS cursors -> clustered writes ----
__global__ __launch_bounds__(256)
void bin_fill_kernel(const int* __restrict__ src, const int* __restrict__ dst,
                     const int* __restrict__ ghist, int2* __restrict__ pairs,
                     int E, int chunk) {
    __shared__ int cur[NBUCK];
    const int tid = threadIdx.x, blk = blockIdx.x;
    for (int u = tid; u < NBUCK; u += 256) cur[u] = ghist[u * NBLK + blk];
    __syncthreads();
    const int e0 = blk * chunk, e1 = min(E, e0 + chunk);
    for (int e = e0 + tid; e < e1; e += 256) {
        int d = dst[e];
        int pos = atomicAdd(&cur[d >> 8], 1);
        pairs[pos] = make_int2(src[e], d & 255);
    }
}

// ---------------- pre-transform: y = x @ w1a (no bias) ----------------
__global__ __launch_bounds__(256)
void pre_kernel(const float* __restrict__ x, const float* __restrict__ wa,
                float* __restrict__ y, int n) {
    __shared__ float s_wa[11 * 64];
    __shared__ float s_row[4][11];
    const int tid = threadIdx.x;
    const int lane = tid & 63;
    const int local = tid >> 6;
    for (int i = tid; i < 11 * 64; i += 256) s_wa[i] = wa[i];
    __syncthreads();
    const int groups = (n + 3) >> 2;
    for (int grp = blockIdx.x; grp < groups; grp += gridDim.x) {
        const int node = grp * 4 + local;
        if (node >= n) continue;
        if (lane < 11) s_row[local][lane] = x[(size_t)node * 11 + lane];
        float acc = 0.f;
        #pragma unroll
        for (int k = 0; k < 11; ++k)
            acc = fmaf(s_row[local][k], s_wa[k * 64 + lane], acc);
        y[((size_t)node << 6) + lane] = acc;
    }
}

// -------- aggregate: bucket-resident LDS accumulator (256 nodes/bucket) ----
// 1024 threads = 16 waves; acc = 64KB LDS (2 blocks/CU = 32 waves/CU).
__global__ __launch_bounds__(1024)
void agg_kernel(const float* __restrict__ y, const int* __restrict__ gbase,
                const int2* __restrict__ pairs, float* __restrict__ out,
                int n) {
    __shared__ float acc[256][64];
    const int u = blockIdx.x;
    const int lane = threadIdx.x & 63;
    const int wid = threadIdx.x >> 6;          // 0..15
    const int node0 = u << 8;
    const int rows = min(256, n - node0);

    for (int r = wid; r < rows; r += 16)       // self term: acc = y rows
        acc[r][lane] = y[((size_t)(node0 + r) << 6) + lane];
    __syncthreads();

    const int base = gbase[u << 8];            // scanned bucket-major hist
    const int end  = gbase[(u + 1) << 8];
    for (int e = base + wid * 4; e < end; e += 64) {
        const int m = end - e;
        int2 p0 = pairs[e];
        int2 p1 = p0, p2 = p0, p3 = p0;
        if (m > 1) p1 = pairs[e + 1];
        if (m > 2) p2 = pairs[e + 2];
        if (m > 3) p3 = pairs[e + 3];
        float v0 = y[((size_t)p0.x << 6) + lane];
        float v1 = y[((size_t)p1.x << 6) + lane];
        float v2 = y[((size_t)p2.x << 6) + lane];
        float v3 = y[((size_t)p3.x << 6) + lane];
        atomicAdd(&acc[p0.y][lane], v0);
        if (m > 1) atomicAdd(&acc[p1.y][lane], v1);
        if (m > 2) atomicAdd(&acc[p2.y][lane], v2);
        if (m > 3) atomicAdd(&acc[p3.y][lane], v3);
    }
    __syncthreads();

    for (int r = wid; r < rows; r += 16)
        out[((size_t)(node0 + r) << 6) + lane] = acc[r][lane];
}

// ------------- MLP: t=relu(bn(a+ba)); z=relu(t@wb+bb); y'=z@wa_next --------
template<bool LAST>
__global__ __launch_bounds__(256)
void mlp_kernel(const float* __restrict__ a,
                const float* __restrict__ ba,
                const float* __restrict__ gam, const float* __restrict__ bet,
                const float* __restrict__ rm, const float* __restrict__ rv,
                const float* __restrict__ wb, const float* __restrict__ bb,
                const float* __restrict__ wn,
                float* __restrict__ out, int n) {
    __shared__ float s_wb[64 * 64];
    __shared__ float s_wn[LAST ? 64 : 64 * 64];
    __shared__ float s_t[4][64];
    __shared__ float s_z[4][64];

    const int tid = threadIdx.x;
    const int lane = tid & 63;
    const int local = tid >> 6;

    for (int i = tid; i < 64 * 64; i += 256) s_wb[i] = wb[i];
    if (!LAST) for (int i = tid; i < 64 * 64; i += 256) s_wn[i] = wn[i];

    const float scale = gam[lane] * rsqrtf(rv[lane] + BN_EPS);
    const float shift = bet[lane] - rm[lane] * scale;
    const float ba_l = ba[lane];
    const float bb_l = bb[lane];
    __syncthreads();

    const int groups = (n + 3) >> 2;
    for (int grp = blockIdx.x; grp < groups; grp += gridDim.x) {
        const int node = grp * 4 + local;
        if (node >= n) continue;
        {
            float t = a[((size_t)node << 6) + lane] + ba_l;
            t = fmaf(t, scale, shift);
            t = fmaxf(t, 0.f);
            s_t[local][lane] = t;
        }
        {
            float acc = bb_l;
            #pragma unroll
            for (int k = 0; k < 64; ++k)
                acc = fmaf(s_t[local][k], s_wb[k * 64 + lane], acc);
            acc = fmaxf(acc, 0.f);
            if (LAST) {
                out[((size_t)node << 6) + lane] = acc;
            } else {
                s_z[local][lane] = acc;
            }
        }
        if (!LAST) {
            float acc = 0.f;
            #pragma unroll
            for (int k = 0; k < 64; ++k)
                acc = fmaf(s_z[local][k], s_wn[k * 64 + lane], acc);
            out[((size_t)node << 6) + lane] = acc;
        }
    }
}

// ---------------- pool: hg[batch[i]] += h[i], batch sorted -----------------
__global__ __launch_bounds__(64)
void pool_kernel(const float* __restrict__ h, const int* __restrict__ batch,
                 float* __restrict__ hg, int n) {
    const int CHUNK = 128;
    const int d = threadIdx.x;
    const int start = blockIdx.x * CHUNK;
    if (start >= n) return;
    const int end = min(start + CHUNK, n);
    float acc = 0.f;
    int cur = batch[start];
    for (int i = start; i < end; ++i) {
        int b = batch[i];
        if (b != cur) {
            atomicAdd(&hg[((size_t)cur << 6) + d], acc);
            acc = 0.f;
            cur = b;
        }
        acc += h[((size_t)i << 6) + d];
    }
    atomicAdd(&hg[((size_t)cur << 6) + d], acc);
}

// ---------------- head: out = relu(hg@lw1+lb1) @ lw2 + lb2 -----------------
__global__ __launch_bounds__(256)
void head_kernel(const float* __restrict__ hg, const float* __restrict__ lw1,
                 const float* __restrict__ lb1, const float* __restrict__ lw2,
                 const float* __restrict__ lb2, float* __restrict__ out,
                 int ngraph) {
    __shared__ float s_w1[64 * 64];
    __shared__ float s_row[4][64];
    const int tid = threadIdx.x;
    const int lane = tid & 63;
    const int local = tid >> 6;
    for (int i = tid; i < 64 * 64; i += 256) s_w1[i] = lw1[i];
    const float b1 = lb1[lane];
    const float w2 = lw2[lane];
    const float b2 = lb2[0];
    __syncthreads();

    const int g = blockIdx.x * 4 + local;
    if (g < ngraph) s_row[local][lane] = hg[((size_t)g << 6) + lane];
    __syncthreads();
    if (g < ngraph) {
        float acc = b1;
        #pragma unroll
        for (int k = 0; k < 64; ++k)
            acc = fmaf(s_row[local][k], s_w1[k * 64 + lane], acc);
        acc = fmaxf(acc, 0.f);
        float r = acc * w2;
        #pragma unroll
        for (int off = 32; off > 0; off >>= 1)
            r += __shfl_down(r, off, 64);
        if (lane == 0) out[g] = r + b2;
    }
}

extern "C" void kernel_launch(void* const* d_in, const int* in_sizes, int n_in,
                              void* d_out, int out_size, void* d_ws, size_t ws_size,
                              hipStream_t stream) {
    const float* x    = (const float*)d_in[0];
    const int* ei     = (const int*)d_in[1];
    const int* batch  = (const int*)d_in[2];
    const int N = in_sizes[0] / 11;
    const int E = in_sizes[1] / 2;
    const int G = out_size;
    const int* src = ei;
    const int* dst = ei + E;

    const float* p[28];
    for (int i = 0; i < 28; ++i) p[i] = (const float*)d_in[3 + i];
    // p[0..7]=L1 {wa,ba,g,be,m,v,wb,bb}, p[8..15]=L2, p[16..23]=L3
    // p[24]=lw1 p[25]=lb1 p[26]=lw2 p[27]=lb2

    float* y     = (float*)d_ws;                    // [N,64]
    float* aggb  = y + (size_t)N * 64;              // [N,64]
    float* y2    = aggb + (size_t)N * 64;           // [N,64]
    int*   ghist = (int*)(y2 + (size_t)N * 64);     // [NBUCK*NBLK] = 131072
    int*   bsum  = ghist + NBUCK * NBLK;            // [512]
    int2*  pairs = (int2*)(bsum + 512);             // [E]
    float* hg    = (float*)(pairs + E);             // [G,64]

    const int chunk   = (E + NBLK - 1) / NBLK;      // edges per binning block
    const int nscan   = NBUCK * NBLK;               // 131072
    const int nbScanB = nscan / 256;                // 512
    const int nbuckUsed = (N + 255) >> 8;           // 391

    // ---- binning (replaces per-node CSR) ----
    bin_hist_kernel<<<NBLK, 256, 0, stream>>>(dst, ghist, E, chunk);
    scan_block_g<<<nbScanB, 256, 0, stream>>>(ghist, bsum, nscan);
    scan_top_kernel<<<1, 512, 0, stream>>>(bsum, nbScanB);
    scan_add_g<<<nbScanB, 256, 0, stream>>>(ghist, bsum, nscan);
    bin_fill_kernel<<<NBLK, 256, 0, stream>>>(src, dst, ghist, pairs, E, chunk);

    // ---- pre-transform y1 = x @ w1a ----
    pre_kernel<<<2048, 256, 0, stream>>>(x, p[0], y, N);

    // ---- layer 1 ----
    agg_kernel<<<nbuckUsed, 1024, 0, stream>>>(y, ghist, pairs, aggb, N);
    mlp_kernel<false><<<2048, 256, 0, stream>>>(aggb, p[1], p[2], p[3], p[4],
        p[5], p[6], p[7], p[8], y, N);
    // ---- layer 2 ----
    agg_kernel<<<nbuckUsed, 1024, 0, stream>>>(y, ghist, pairs, aggb, N);
    mlp_kernel<false><<<2048, 256, 0, stream>>>(aggb, p[9], p[10], p[11], p[12],
        p[13], p[14], p[15], p[16], y, N);
    // ---- layer 3 ----
    agg_kernel<<<nbuckUsed, 1024, 0, stream>>>(y, ghist, pairs, aggb, N);
    mlp_kernel<true><<<2048, 256, 0, stream>>>(aggb, p[17], p[18], p[19], p[20],
        p[21], p[22], p[23], nullptr, y2, N);

    // ---- pool ----
    hipMemsetAsync(hg, 0, (size_t)G * 64 * sizeof(float), stream);
    pool_kernel<<<(N + 127) / 128, 64, 0, stream>>>(y2, batch, hg, N);

    // ---- head ----
    head_kernel<<<(G + 3) / 4, 256, 0, stream>>>(hg,
        p[24], p[25], p[26], p[27], (float*)d_out, G);
}

// Round 5
// 449.834 us; speedup vs baseline: 4.0944x; 4.0944x over previous
//
#include <hip/hip_runtime.h>

// GIN forward: transformed-space linearity (y = h@wa; agg@wa = y_self + sum y_nbr)
// CSR via bucket binning + per-bucket counting sort (clustered writes),
// per-node wave gather agg (no LDS, 8-deep ILP), streaming MLP, pool, head.
// fp32 throughout. N=100000, E=1200000, DIM=64, G=1000, IN=11.

#define BN_EPS 1e-5f
#define NBUCK 512          // power-of-2 >= ceil(N/256)
#define NBLK  256          // binning blocks

// ---------------- binning: per-block histogram (bucket-major layout) -------
__global__ __launch_bounds__(256)
void bin_hist_kernel(const int* __restrict__ dst, int* __restrict__ ghist,
                     int E, int chunk) {
    __shared__ int h[NBUCK];
    const int tid = threadIdx.x, blk = blockIdx.x;
    for (int u = tid; u < NBUCK; u += 256) h[u] = 0;
    __syncthreads();
    const int e0 = blk * chunk, e1 = min(E, e0 + chunk);
    for (int e = e0 + tid; e < e1; e += 256)
        atomicAdd(&h[dst[e] >> 8], 1);
    __syncthreads();
    for (int u = tid; u < NBUCK; u += 256)
        ghist[u * NBLK + blk] = h[u];     // bucket-major
}

// ---------------- hierarchical exclusive scan ------------------------------
__global__ __launch_bounds__(256)
void scan_block_g(int* __restrict__ a, int* __restrict__ bsum, int n) {
    __shared__ int s[256];
    int i = blockIdx.x * 256 + threadIdx.x;
    int v = (i < n) ? a[i] : 0;
    s[threadIdx.x] = v;
    __syncthreads();
    for (int off = 1; off < 256; off <<= 1) {
        int t = (threadIdx.x >= off) ? s[threadIdx.x - off] : 0;
        __syncthreads();
        s[threadIdx.x] += t;
        __syncthreads();
    }
    if (i < n) a[i] = s[threadIdx.x] - v;
    if (threadIdx.x == 255) bsum[blockIdx.x] = s[255];
}

__global__ __launch_bounds__(512)
void scan_top_kernel(int* bsum, int nb) {
    __shared__ int s[512];
    int v = (threadIdx.x < nb) ? bsum[threadIdx.x] : 0;
    s[threadIdx.x] = v;
    __syncthreads();
    for (int off = 1; off < 512; off <<= 1) {
        int t = (threadIdx.x >= off) ? s[threadIdx.x - off] : 0;
        __syncthreads();
        s[threadIdx.x] += t;
        __syncthreads();
    }
    if (threadIdx.x < nb) bsum[threadIdx.x] = s[threadIdx.x] - v;
}

// ------- bin fill: block-local LDS cursors -> clustered pair writes --------
// global scanned offset = ghist[u*NBLK+blk] + bsum[u]  (bsum folded in here)
__global__ __launch_bounds__(256)
void bin_fill_kernel(const int* __restrict__ src, const int* __restrict__ dst,
                     const int* __restrict__ ghist, const int* __restrict__ bsum,
                     int2* __restrict__ pairs, int E, int chunk) {
    __shared__ int cur[NBUCK];
    const int tid = threadIdx.x, blk = blockIdx.x;
    for (int u = tid; u < NBUCK; u += 256)
        cur[u] = ghist[u * NBLK + blk] + bsum[u];
    __syncthreads();
    const int e0 = blk * chunk, e1 = min(E, e0 + chunk);
    for (int e = e0 + tid; e < e1; e += 256) {
        int d = dst[e];
        int pos = atomicAdd(&cur[d >> 8], 1);
        pairs[pos] = make_int2(src[e], d & 255);
    }
}

// ------- per-bucket counting sort -> per-node CSR (col, rp) ----------------
// block = bucket; all col writes land in bucket's contiguous range.
__global__ __launch_bounds__(256)
void csr_sort_kernel(const int2* __restrict__ pairs, const int* __restrict__ bsum,
                     int* __restrict__ col, int* __restrict__ rp,
                     int N, int E, int nbuckUsed) {
    __shared__ int cnt[256];
    __shared__ int cur[256];
    const int u = blockIdx.x, tid = threadIdx.x;
    const int base = bsum[u];
    const int end  = (u == NBUCK - 1) ? E : bsum[u + 1];
    const int node0 = u << 8;
    const int rows = min(256, N - node0);

    cnt[tid] = 0;
    __syncthreads();
    for (int e = base + tid; e < end; e += 256)
        atomicAdd(&cnt[pairs[e].y], 1);
    __syncthreads();
    // exclusive scan of cnt
    int own = cnt[tid];
    int inc = own;
    __syncthreads();
    cnt[tid] = inc;
    __syncthreads();
    for (int off = 1; off < 256; off <<= 1) {
        int t = (tid >= off) ? cnt[tid - off] : 0;
        __syncthreads();
        cnt[tid] += t;
        __syncthreads();
    }
    const int excl = cnt[tid] - own;
    if (tid < rows) rp[node0 + tid] = base + excl;
    if (tid == 0 && u == nbuckUsed - 1) rp[N] = E;
    cur[tid] = base + excl;
    __syncthreads();
    for (int e = base + tid; e < end; e += 256) {
        int2 p = pairs[e];
        int pos = atomicAdd(&cur[p.y], 1);
        col[pos] = p.x;
    }
}

// ---------------- pre-transform: y = x @ w1a (no bias) ----------------
__global__ __launch_bounds__(256)
void pre_kernel(const float* __restrict__ x, const float* __restrict__ wa,
                float* __restrict__ y, int n) {
    __shared__ float s_wa[11 * 64];
    __shared__ float s_row[4][11];
    const int tid = threadIdx.x;
    const int lane = tid & 63;
    const int local = tid >> 6;
    for (int i = tid; i < 11 * 64; i += 256) s_wa[i] = wa[i];
    __syncthreads();
    const int groups = (n + 3) >> 2;
    for (int grp = blockIdx.x; grp < groups; grp += gridDim.x) {
        const int node = grp * 4 + local;
        if (node >= n) continue;
        if (lane < 11) s_row[local][lane] = x[(size_t)node * 11 + lane];
        float acc = 0.f;
        #pragma unroll
        for (int k = 0; k < 11; ++k)
            acc = fmaf(s_row[local][k], s_wa[k * 64 + lane], acc);
        y[((size_t)node << 6) + lane] = acc;
    }
}

// ------------- aggregate: a[i] = y[i] + sum_{j->i} y[j] --------------------
// wave = node, lane = feature; no LDS; 8 predicated gathers in flight.
__global__ __launch_bounds__(256, 8)
void agg_kernel(const float* __restrict__ y, const int* __restrict__ rp,
                const int* __restrict__ col, float* __restrict__ out, int n) {
    const int node = (blockIdx.x * 256 + threadIdx.x) >> 6;
    if (node >= n) return;
    const int lane = threadIdx.x & 63;
    const int beg = rp[node], end = rp[node + 1];
    float agg = y[((size_t)node << 6) + lane];
    for (int i = beg; i < end; i += 8) {
        int   idx[8];
        float v[8];
        #pragma unroll
        for (int j = 0; j < 8; ++j)
            idx[j] = (i + j < end) ? col[i + j] : -1;
        #pragma unroll
        for (int j = 0; j < 8; ++j)
            v[j] = (idx[j] >= 0) ? y[((size_t)idx[j] << 6) + lane] : 0.f;
        #pragma unroll
        for (int j = 0; j < 8; ++j)
            agg += v[j];
    }
    out[((size_t)node << 6) + lane] = agg;
}

// ------------- MLP: t=relu(bn(a+ba)); z=relu(t@wb+bb); y'=z@wa_next --------
template<bool LAST>
__global__ __launch_bounds__(256)
void mlp_kernel(const float* __restrict__ a,
                const float* __restrict__ ba,
                const float* __restrict__ gam, const float* __restrict__ bet,
                const float* __restrict__ rm, const float* __restrict__ rv,
                const float* __restrict__ wb, const float* __restrict__ bb,
                const float* __restrict__ wn,
                float* __restrict__ out, int n) {
    __shared__ float s_wb[64 * 64];
    __shared__ float s_wn[LAST ? 64 : 64 * 64];
    __shared__ float s_t[4][64];
    __shared__ float s_z[4][64];

    const int tid = threadIdx.x;
    const int lane = tid & 63;
    const int local = tid >> 6;

    for (int i = tid; i < 64 * 64; i += 256) s_wb[i] = wb[i];
    if (!LAST) for (int i = tid; i < 64 * 64; i += 256) s_wn[i] = wn[i];

    const float scale = gam[lane] * rsqrtf(rv[lane] + BN_EPS);
    const float shift = bet[lane] - rm[lane] * scale;
    const float ba_l = ba[lane];
    const float bb_l = bb[lane];
    __syncthreads();

    const int groups = (n + 3) >> 2;
    for (int grp = blockIdx.x; grp < groups; grp += gridDim.x) {
        const int node = grp * 4 + local;
        if (node >= n) continue;
        {
            float t = a[((size_t)node << 6) + lane] + ba_l;
            t = fmaf(t, scale, shift);
            t = fmaxf(t, 0.f);
            s_t[local][lane] = t;
        }
        {
            float acc = bb_l;
            #pragma unroll
            for (int k = 0; k < 64; ++k)
                acc = fmaf(s_t[local][k], s_wb[k * 64 + lane], acc);
            acc = fmaxf(acc, 0.f);
            if (LAST) {
                out[((size_t)node << 6) + lane] = acc;
            } else {
                s_z[local][lane] = acc;
            }
        }
        if (!LAST) {
            float acc = 0.f;
            #pragma unroll
            for (int k = 0; k < 64; ++k)
                acc = fmaf(s_z[local][k], s_wn[k * 64 + lane], acc);
            out[((size_t)node << 6) + lane] = acc;
        }
    }
}

// ---------------- pool: hg[batch[i]] += h[i], batch sorted -----------------
__global__ __launch_bounds__(64)
void pool_kernel(const float* __restrict__ h, const int* __restrict__ batch,
                 float* __restrict__ hg, int n) {
    const int CHUNK = 128;
    const int d = threadIdx.x;
    const int start = blockIdx.x * CHUNK;
    if (start >= n) return;
    const int end = min(start + CHUNK, n);
    float acc = 0.f;
    int cur = batch[start];
    for (int i = start; i < end; ++i) {
        int b = batch[i];
        if (b != cur) {
            atomicAdd(&hg[((size_t)cur << 6) + d], acc);
            acc = 0.f;
            cur = b;
        }
        acc += h[((size_t)i << 6) + d];
    }
    atomicAdd(&hg[((size_t)cur << 6) + d], acc);
}

// ---------------- head: out = relu(hg@lw1+lb1) @ lw2 + lb2 -----------------
__global__ __launch_bounds__(256)
void head_kernel(const float* __restrict__ hg, const float* __restrict__ lw1,
                 const float* __restrict__ lb1, const float* __restrict__ lw2,
                 const float* __restrict__ lb2, float* __restrict__ out,
                 int ngraph) {
    __shared__ float s_w1[64 * 64];
    __shared__ float s_row[4][64];
    const int tid = threadIdx.x;
    const int lane = tid & 63;
    const int local = tid >> 6;
    for (int i = tid; i < 64 * 64; i += 256) s_w1[i] = lw1[i];
    const float b1 = lb1[lane];
    const float w2 = lw2[lane];
    const float b2 = lb2[0];
    __syncthreads();

    const int g = blockIdx.x * 4 + local;
    if (g < ngraph) s_row[local][lane] = hg[((size_t)g << 6) + lane];
    __syncthreads();
    if (g < ngraph) {
        float acc = b1;
        #pragma unroll
        for (int k = 0; k < 64; ++k)
            acc = fmaf(s_row[local][k], s_w1[k * 64 + lane], acc);
        acc = fmaxf(acc, 0.f);
        float r = acc * w2;
        #pragma unroll
        for (int off = 32; off > 0; off >>= 1)
            r += __shfl_down(r, off, 64);
        if (lane == 0) out[g] = r + b2;
    }
}

extern "C" void kernel_launch(void* const* d_in, const int* in_sizes, int n_in,
                              void* d_out, int out_size, void* d_ws, size_t ws_size,
                              hipStream_t stream) {
    const float* x    = (const float*)d_in[0];
    const int* ei     = (const int*)d_in[1];
    const int* batch  = (const int*)d_in[2];
    const int N = in_sizes[0] / 11;
    const int E = in_sizes[1] / 2;
    const int G = out_size;
    const int* src = ei;
    const int* dst = ei + E;

    const float* p[28];
    for (int i = 0; i < 28; ++i) p[i] = (const float*)d_in[3 + i];
    // p[0..7]=L1 {wa,ba,g,be,m,v,wb,bb}, p[8..15]=L2, p[16..23]=L3
    // p[24]=lw1 p[25]=lb1 p[26]=lw2 p[27]=lb2

    float* y     = (float*)d_ws;                    // [N,64]
    float* aggb  = y + (size_t)N * 64;              // [N,64]
    float* y2    = aggb + (size_t)N * 64;           // [N,64]
    int*   ghist = (int*)(y2 + (size_t)N * 64);     // [NBUCK*NBLK]
    int*   bsum  = ghist + NBUCK * NBLK;            // [512]
    int*   rp    = bsum + 512;                      // [N+1]
    int*   col   = rp + N + 1;                      // [E]
    int2*  pairs = (int2*)(col + E);                // [E]
    float* hg    = (float*)(pairs + E);             // [G,64]

    const int chunk     = (E + NBLK - 1) / NBLK;
    const int nscan     = NBUCK * NBLK;             // 131072
    const int nbScanB   = nscan / 256;              // 512
    const int nbuckUsed = (N + 255) >> 8;           // 391
    const int nbNode    = (N * 64 + 255) / 256;     // wave = node

    // ---- CSR build: bucket binning + per-bucket counting sort ----
    bin_hist_kernel<<<NBLK, 256, 0, stream>>>(dst, ghist, E, chunk);
    scan_block_g<<<nbScanB, 256, 0, stream>>>(ghist, bsum, nscan);
    scan_top_kernel<<<1, 512, 0, stream>>>(bsum, nbScanB);
    bin_fill_kernel<<<NBLK, 256, 0, stream>>>(src, dst, ghist, bsum, pairs, E, chunk);
    csr_sort_kernel<<<nbuckUsed, 256, 0, stream>>>(pairs, bsum, col, rp, N, E, nbuckUsed);

    // ---- pre-transform y1 = x @ w1a ----
    pre_kernel<<<2048, 256, 0, stream>>>(x, p[0], y, N);

    // ---- layer 1 ----
    agg_kernel<<<nbNode, 256, 0, stream>>>(y, rp, col, aggb, N);
    mlp_kernel<false><<<2048, 256, 0, stream>>>(aggb, p[1], p[2], p[3], p[4],
        p[5], p[6], p[7], p[8], y, N);
    // ---- layer 2 ----
    agg_kernel<<<nbNode, 256, 0, stream>>>(y, rp, col, aggb, N);
    mlp_kernel<false><<<2048, 256, 0, stream>>>(aggb, p[9], p[10], p[11], p[12],
        p[13], p[14], p[15], p[16], y, N);
    // ---- layer 3 ----
    agg_kernel<<<nbNode, 256, 0, stream>>>(y, rp, col, aggb, N);
    mlp_kernel<true><<<2048, 256, 0, stream>>>(aggb, p[17], p[18], p[19], p[20],
        p[21], p[22], p[23], nullptr, y2, N);

    // ---- pool ----
    hipMemsetAsync(hg, 0, (size_t)G * 64 * sizeof(float), stream);
    pool_kernel<<<(N + 127) / 128, 64, 0, stream>>>(y2, batch, hg, N);

    // ---- head ----
    head_kernel<<<(G + 3) / 4, 256, 0, stream>>>(hg,
        p[24], p[25], p[26], p[27], (float*)d_out, G);
}

// Round 6
// 363.145 us; speedup vs baseline: 5.0718x; 1.2387x over previous
//
#include <hip/hip_runtime.h>

// GIN forward: transformed-space linearity (y = h@wa; agg@wa = y_self + sum y_nbr)
// CSR via bucket binning + per-bucket counting sort (clustered writes),
// per-node wave gather agg (no LDS, 8-deep ILP),
// register-weight MLP (weights in VGPRs, activations via LDS broadcast),
// pool, head. fp32 throughout. N=100000, E=1200000, DIM=64, G=1000, IN=11.

#define BN_EPS 1e-5f
#define NBUCK 512          // power-of-2 >= ceil(N/256)
#define NBLK  256          // binning blocks

// ---------------- binning: per-block histogram (bucket-major layout) -------
__global__ __launch_bounds__(256)
void bin_hist_kernel(const int* __restrict__ dst, int* __restrict__ ghist,
                     int E, int chunk) {
    __shared__ int h[NBUCK];
    const int tid = threadIdx.x, blk = blockIdx.x;
    for (int u = tid; u < NBUCK; u += 256) h[u] = 0;
    __syncthreads();
    const int e0 = blk * chunk, e1 = min(E, e0 + chunk);
    for (int e = e0 + tid; e < e1; e += 256)
        atomicAdd(&h[dst[e] >> 8], 1);
    __syncthreads();
    for (int u = tid; u < NBUCK; u += 256)
        ghist[u * NBLK + blk] = h[u];     // bucket-major
}

// ---------------- hierarchical exclusive scan ------------------------------
__global__ __launch_bounds__(256)
void scan_block_g(int* __restrict__ a, int* __restrict__ bsum, int n) {
    __shared__ int s[256];
    int i = blockIdx.x * 256 + threadIdx.x;
    int v = (i < n) ? a[i] : 0;
    s[threadIdx.x] = v;
    __syncthreads();
    for (int off = 1; off < 256; off <<= 1) {
        int t = (threadIdx.x >= off) ? s[threadIdx.x - off] : 0;
        __syncthreads();
        s[threadIdx.x] += t;
        __syncthreads();
    }
    if (i < n) a[i] = s[threadIdx.x] - v;
    if (threadIdx.x == 255) bsum[blockIdx.x] = s[255];
}

__global__ __launch_bounds__(512)
void scan_top_kernel(int* bsum, int nb) {
    __shared__ int s[512];
    int v = (threadIdx.x < nb) ? bsum[threadIdx.x] : 0;
    s[threadIdx.x] = v;
    __syncthreads();
    for (int off = 1; off < 512; off <<= 1) {
        int t = (threadIdx.x >= off) ? s[threadIdx.x - off] : 0;
        __syncthreads();
        s[threadIdx.x] += t;
        __syncthreads();
    }
    if (threadIdx.x < nb) bsum[threadIdx.x] = s[threadIdx.x] - v;
}

// ------- bin fill: block-local LDS cursors -> clustered pair writes --------
__global__ __launch_bounds__(256)
void bin_fill_kernel(const int* __restrict__ src, const int* __restrict__ dst,
                     const int* __restrict__ ghist, const int* __restrict__ bsum,
                     int2* __restrict__ pairs, int E, int chunk) {
    __shared__ int cur[NBUCK];
    const int tid = threadIdx.x, blk = blockIdx.x;
    for (int u = tid; u < NBUCK; u += 256)
        cur[u] = ghist[u * NBLK + blk] + bsum[u];
    __syncthreads();
    const int e0 = blk * chunk, e1 = min(E, e0 + chunk);
    for (int e = e0 + tid; e < e1; e += 256) {
        int d = dst[e];
        int pos = atomicAdd(&cur[d >> 8], 1);
        pairs[pos] = make_int2(src[e], d & 255);
    }
}

// ------- per-bucket counting sort -> per-node CSR (col, rp) ----------------
__global__ __launch_bounds__(256)
void csr_sort_kernel(const int2* __restrict__ pairs, const int* __restrict__ bsum,
                     int* __restrict__ col, int* __restrict__ rp,
                     int N, int E, int nbuckUsed) {
    __shared__ int cnt[256];
    __shared__ int cur[256];
    const int u = blockIdx.x, tid = threadIdx.x;
    const int base = bsum[u];
    const int end  = (u == NBUCK - 1) ? E : bsum[u + 1];
    const int node0 = u << 8;
    const int rows = min(256, N - node0);

    cnt[tid] = 0;
    __syncthreads();
    for (int e = base + tid; e < end; e += 256)
        atomicAdd(&cnt[pairs[e].y], 1);
    __syncthreads();
    int own = cnt[tid];
    __syncthreads();
    cnt[tid] = own;
    __syncthreads();
    for (int off = 1; off < 256; off <<= 1) {
        int t = (tid >= off) ? cnt[tid - off] : 0;
        __syncthreads();
        cnt[tid] += t;
        __syncthreads();
    }
    const int excl = cnt[tid] - own;
    if (tid < rows) rp[node0 + tid] = base + excl;
    if (tid == 0 && u == nbuckUsed - 1) rp[N] = E;
    cur[tid] = base + excl;
    __syncthreads();
    for (int e = base + tid; e < end; e += 256) {
        int2 p = pairs[e];
        int pos = atomicAdd(&cur[p.y], 1);
        col[pos] = p.x;
    }
}

// ---------------- pre-transform: y = x @ w1a (no bias) ----------------
__global__ __launch_bounds__(256)
void pre_kernel(const float* __restrict__ x, const float* __restrict__ wa,
                float* __restrict__ y, int n) {
    __shared__ float s_wa[11 * 64];
    __shared__ float s_row[4][11];
    const int tid = threadIdx.x;
    const int lane = tid & 63;
    const int local = tid >> 6;
    for (int i = tid; i < 11 * 64; i += 256) s_wa[i] = wa[i];
    __syncthreads();
    const int groups = (n + 3) >> 2;
    for (int grp = blockIdx.x; grp < groups; grp += gridDim.x) {
        const int node = grp * 4 + local;
        if (node >= n) continue;
        if (lane < 11) s_row[local][lane] = x[(size_t)node * 11 + lane];
        float acc = 0.f;
        #pragma unroll
        for (int k = 0; k < 11; ++k)
            acc = fmaf(s_row[local][k], s_wa[k * 64 + lane], acc);
        y[((size_t)node << 6) + lane] = acc;
    }
}

// ------------- aggregate: a[i] = y[i] + sum_{j->i} y[j] --------------------
__global__ __launch_bounds__(256, 8)
void agg_kernel(const float* __restrict__ y, const int* __restrict__ rp,
                const int* __restrict__ col, float* __restrict__ out, int n) {
    const int node = (blockIdx.x * 256 + threadIdx.x) >> 6;
    if (node >= n) return;
    const int lane = threadIdx.x & 63;
    const int beg = rp[node], end = rp[node + 1];
    float agg = y[((size_t)node << 6) + lane];
    for (int i = beg; i < end; i += 8) {
        int   idx[8];
        float v[8];
        #pragma unroll
        for (int j = 0; j < 8; ++j)
            idx[j] = (i + j < end) ? col[i + j] : -1;
        #pragma unroll
        for (int j = 0; j < 8; ++j)
            v[j] = (idx[j] >= 0) ? y[((size_t)idx[j] << 6) + lane] : 0.f;
        #pragma unroll
        for (int j = 0; j < 8; ++j)
            agg += v[j];
    }
    out[((size_t)node << 6) + lane] = agg;
}

// ------------- MLP: t=relu(bn(a+ba)); z=relu(t@wb+bb); y'=z@wa_next --------
// Weights live in VGPRs (lane = output feature -> lane's column). Activations
// cross lanes via wave-private LDS rows read as same-address float4 broadcasts.
template<bool LAST>
__global__ __launch_bounds__(256, 3)
void mlp_kernel(const float* __restrict__ a,
                const float* __restrict__ ba,
                const float* __restrict__ gam, const float* __restrict__ bet,
                const float* __restrict__ rm, const float* __restrict__ rv,
                const float* __restrict__ wb, const float* __restrict__ bb,
                const float* __restrict__ wn,
                float* __restrict__ out, int n) {
    __shared__ float s_t[4][64];
    __shared__ float s_z[4][64];

    const int tid = threadIdx.x;
    const int lane = tid & 63;
    const int local = tid >> 6;

    // weight columns into registers (coalesced loads, L2-resident)
    float wbr[64];
    #pragma unroll
    for (int k = 0; k < 64; ++k) wbr[k] = wb[k * 64 + lane];
    float wnr[LAST ? 1 : 64];
    if (!LAST) {
        #pragma unroll
        for (int k = 0; k < 64; ++k) wnr[k] = wn[k * 64 + lane];
    }

    const float scale = gam[lane] * rsqrtf(rv[lane] + BN_EPS);
    const float shift = bet[lane] - rm[lane] * scale;
    const float ba_l = ba[lane];
    const float bb_l = bb[lane];

    const int groups = (n + 3) >> 2;
    for (int grp = blockIdx.x; grp < groups; grp += gridDim.x) {
        const int node = grp * 4 + local;
        if (node >= n) continue;
        {
            float t = a[((size_t)node << 6) + lane] + ba_l;
            t = fmaf(t, scale, shift);
            t = fmaxf(t, 0.f);
            s_t[local][lane] = t;
        }
        float zv;
        {
            float acc = bb_l;
            const float4* pt = (const float4*)(&s_t[local][0]);
            #pragma unroll
            for (int q = 0; q < 16; ++q) {
                float4 tv = pt[q];                 // same-addr broadcast b128
                acc = fmaf(tv.x, wbr[4 * q + 0], acc);
                acc = fmaf(tv.y, wbr[4 * q + 1], acc);
                acc = fmaf(tv.z, wbr[4 * q + 2], acc);
                acc = fmaf(tv.w, wbr[4 * q + 3], acc);
            }
            zv = fmaxf(acc, 0.f);
        }
        if (LAST) {
            out[((size_t)node << 6) + lane] = zv;
        } else {
            s_z[local][lane] = zv;
            float acc = 0.f;
            const float4* pz = (const float4*)(&s_z[local][0]);
            #pragma unroll
            for (int q = 0; q < 16; ++q) {
                float4 zv4 = pz[q];
                acc = fmaf(zv4.x, wnr[4 * q + 0], acc);
                acc = fmaf(zv4.y, wnr[4 * q + 1], acc);
                acc = fmaf(zv4.z, wnr[4 * q + 2], acc);
                acc = fmaf(zv4.w, wnr[4 * q + 3], acc);
            }
            out[((size_t)node << 6) + lane] = acc;
        }
    }
}

// ---------------- pool: hg[batch[i]] += h[i], batch sorted -----------------
__global__ __launch_bounds__(64)
void pool_kernel(const float* __restrict__ h, const int* __restrict__ batch,
                 float* __restrict__ hg, int n) {
    const int CHUNK = 128;
    const int d = threadIdx.x;
    const int start = blockIdx.x * CHUNK;
    if (start >= n) return;
    const int end = min(start + CHUNK, n);
    float acc = 0.f;
    int cur = batch[start];
    for (int i = start; i < end; ++i) {
        int b = batch[i];
        if (b != cur) {
            atomicAdd(&hg[((size_t)cur << 6) + d], acc);
            acc = 0.f;
            cur = b;
        }
        acc += h[((size_t)i << 6) + d];
    }
    atomicAdd(&hg[((size_t)cur << 6) + d], acc);
}

// ---------------- head: out = relu(hg@lw1+lb1) @ lw2 + lb2 -----------------
__global__ __launch_bounds__(256)
void head_kernel(const float* __restrict__ hg, const float* __restrict__ lw1,
                 const float* __restrict__ lb1, const float* __restrict__ lw2,
                 const float* __restrict__ lb2, float* __restrict__ out,
                 int ngraph) {
    __shared__ float s_w1[64 * 64];
    __shared__ float s_row[4][64];
    const int tid = threadIdx.x;
    const int lane = tid & 63;
    const int local = tid >> 6;
    for (int i = tid; i < 64 * 64; i += 256) s_w1[i] = lw1[i];
    const float b1 = lb1[lane];
    const float w2 = lw2[lane];
    const float b2 = lb2[0];
    __syncthreads();

    const int g = blockIdx.x * 4 + local;
    if (g < ngraph) s_row[local][lane] = hg[((size_t)g << 6) + lane];
    __syncthreads();
    if (g < ngraph) {
        float acc = b1;
        #pragma unroll
        for (int k = 0; k < 64; ++k)
            acc = fmaf(s_row[local][k], s_w1[k * 64 + lane], acc);
        acc = fmaxf(acc, 0.f);
        float r = acc * w2;
        #pragma unroll
        for (int off = 32; off > 0; off >>= 1)
            r += __shfl_down(r, off, 64);
        if (lane == 0) out[g] = r + b2;
    }
}

extern "C" void kernel_launch(void* const* d_in, const int* in_sizes, int n_in,
                              void* d_out, int out_size, void* d_ws, size_t ws_size,
                              hipStream_t stream) {
    const float* x    = (const float*)d_in[0];
    const int* ei     = (const int*)d_in[1];
    const int* batch  = (const int*)d_in[2];
    const int N = in_sizes[0] / 11;
    const int E = in_sizes[1] / 2;
    const int G = out_size;
    const int* src = ei;
    const int* dst = ei + E;

    const float* p[28];
    for (int i = 0; i < 28; ++i) p[i] = (const float*)d_in[3 + i];
    // p[0..7]=L1 {wa,ba,g,be,m,v,wb,bb}, p[8..15]=L2, p[16..23]=L3
    // p[24]=lw1 p[25]=lb1 p[26]=lw2 p[27]=lb2

    float* y     = (float*)d_ws;                    // [N,64]
    float* aggb  = y + (size_t)N * 64;              // [N,64]
    float* y2    = aggb + (size_t)N * 64;           // [N,64]
    int*   ghist = (int*)(y2 + (size_t)N * 64);     // [NBUCK*NBLK]
    int*   bsum  = ghist + NBUCK * NBLK;            // [512]
    int*   rp    = bsum + 512;                      // [N+1]
    int*   col   = rp + N + 1;                      // [E]
    int2*  pairs = (int2*)(col + E);                // [E]
    float* hg    = (float*)(pairs + E);             // [G,64]

    const int chunk     = (E + NBLK - 1) / NBLK;
    const int nscan     = NBUCK * NBLK;             // 131072
    const int nbScanB   = nscan / 256;              // 512
    const int nbuckUsed = (N + 255) >> 8;           // 391
    const int nbNode    = (N * 64 + 255) / 256;     // wave = node

    // ---- CSR build: bucket binning + per-bucket counting sort ----
    bin_hist_kernel<<<NBLK, 256, 0, stream>>>(dst, ghist, E, chunk);
    scan_block_g<<<nbScanB, 256, 0, stream>>>(ghist, bsum, nscan);
    scan_top_kernel<<<1, 512, 0, stream>>>(bsum, nbScanB);
    bin_fill_kernel<<<NBLK, 256, 0, stream>>>(src, dst, ghist, bsum, pairs, E, chunk);
    csr_sort_kernel<<<nbuckUsed, 256, 0, stream>>>(pairs, bsum, col, rp, N, E, nbuckUsed);

    // ---- pre-transform y1 = x @ w1a ----
    pre_kernel<<<2048, 256, 0, stream>>>(x, p[0], y, N);

    // ---- layer 1 ----
    agg_kernel<<<nbNode, 256, 0, stream>>>(y, rp, col, aggb, N);
    mlp_kernel<false><<<2048, 256, 0, stream>>>(aggb, p[1], p[2], p[3], p[4],
        p[5], p[6], p[7], p[8], y, N);
    // ---- layer 2 ----
    agg_kernel<<<nbNode, 256, 0, stream>>>(y, rp, col, aggb, N);
    mlp_kernel<false><<<2048, 256, 0, stream>>>(aggb, p[9], p[10], p[11], p[12],
        p[13], p[14], p[15], p[16], y, N);
    // ---- layer 3 ----
    agg_kernel<<<nbNode, 256, 0, stream>>>(y, rp, col, aggb, N);
    mlp_kernel<true><<<2048, 256, 0, stream>>>(aggb, p[17], p[18], p[19], p[20],
        p[21], p[22], p[23], nullptr, y2, N);

    // ---- pool ----
    hipMemsetAsync(hg, 0, (size_t)G * 64 * sizeof(float), stream);
    pool_kernel<<<(N + 127) / 128, 64, 0, stream>>>(y2, batch, hg, N);

    // ---- head ----
    head_kernel<<<(G + 3) / 4, 256, 0, stream>>>(hg,
        p[24], p[25], p[26], p[27], (float*)d_out, G);
}

// Round 7
// 349.738 us; speedup vs baseline: 5.2662x; 1.0383x over previous
//
#include <hip/hip_runtime.h>

// GIN forward: transformed-space linearity (y = h@wa; agg@wa = y_self + sum y_nbr)
// y table stored bf16 (gather BW), CSR via bucket binning + counting sort,
// scalarized wave-per-node gather agg, readlane-broadcast register MLP,
// pool, head. N=100000, E=1200000, DIM=64, G=1000, IN=11.

#define BN_EPS 1e-5f
#define NBUCK 512
#define NBLK  256

typedef unsigned short ushort_t;

__device__ __forceinline__ ushort_t f2bf(float x) {
    unsigned u = __float_as_uint(x);
    unsigned r = (u + 0x7FFF + ((u >> 16) & 1)) >> 16;   // RNE
    return (ushort_t)r;
}
__device__ __forceinline__ float bf2f(ushort_t b) {
    return __uint_as_float((unsigned)b << 16);
}
__device__ __forceinline__ float lanebcast(float v, int k) {
    return __uint_as_float(__builtin_amdgcn_readlane(__float_as_uint(v), k));
}

// ---------------- binning: per-block histogram (bucket-major layout) -------
__global__ __launch_bounds__(256)
void bin_hist_kernel(const int* __restrict__ dst, int* __restrict__ ghist,
                     int E, int chunk) {
    __shared__ int h[NBUCK];
    const int tid = threadIdx.x, blk = blockIdx.x;
    for (int u = tid; u < NBUCK; u += 256) h[u] = 0;
    __syncthreads();
    const int e0 = blk * chunk, e1 = min(E, e0 + chunk);
    for (int e = e0 + tid; e < e1; e += 256)
        atomicAdd(&h[dst[e] >> 8], 1);
    __syncthreads();
    for (int u = tid; u < NBUCK; u += 256)
        ghist[u * NBLK + blk] = h[u];
}

// ---------------- hierarchical exclusive scan ------------------------------
__global__ __launch_bounds__(256)
void scan_block_g(int* __restrict__ a, int* __restrict__ bsum, int n) {
    __shared__ int s[256];
    int i = blockIdx.x * 256 + threadIdx.x;
    int v = (i < n) ? a[i] : 0;
    s[threadIdx.x] = v;
    __syncthreads();
    for (int off = 1; off < 256; off <<= 1) {
        int t = (threadIdx.x >= off) ? s[threadIdx.x - off] : 0;
        __syncthreads();
        s[threadIdx.x] += t;
        __syncthreads();
    }
    if (i < n) a[i] = s[threadIdx.x] - v;
    if (threadIdx.x == 255) bsum[blockIdx.x] = s[255];
}

__global__ __launch_bounds__(512)
void scan_top_kernel(int* bsum, int nb) {
    __shared__ int s[512];
    int v = (threadIdx.x < nb) ? bsum[threadIdx.x] : 0;
    s[threadIdx.x] = v;
    __syncthreads();
    for (int off = 1; off < 512; off <<= 1) {
        int t = (threadIdx.x >= off) ? s[threadIdx.x - off] : 0;
        __syncthreads();
        s[threadIdx.x] += t;
        __syncthreads();
    }
    if (threadIdx.x < nb) bsum[threadIdx.x] = s[threadIdx.x] - v;
}

// ------- bin fill: block-local LDS cursors -> clustered pair writes --------
__global__ __launch_bounds__(256)
void bin_fill_kernel(const int* __restrict__ src, const int* __restrict__ dst,
                     const int* __restrict__ ghist, const int* __restrict__ bsum,
                     int2* __restrict__ pairs, int E, int chunk) {
    __shared__ int cur[NBUCK];
    const int tid = threadIdx.x, blk = blockIdx.x;
    for (int u = tid; u < NBUCK; u += 256)
        cur[u] = ghist[u * NBLK + blk] + bsum[u];
    __syncthreads();
    const int e0 = blk * chunk, e1 = min(E, e0 + chunk);
    for (int e = e0 + tid; e < e1; e += 256) {
        int d = dst[e];
        int pos = atomicAdd(&cur[d >> 8], 1);
        pairs[pos] = make_int2(src[e], d & 255);
    }
}

// ------- per-bucket counting sort -> per-node CSR (col, rp) ----------------
__global__ __launch_bounds__(256)
void csr_sort_kernel(const int2* __restrict__ pairs, const int* __restrict__ bsum,
                     int* __restrict__ col, int* __restrict__ rp,
                     int N, int E, int nbuckUsed) {
    __shared__ int cnt[256];
    __shared__ int cur[256];
    const int u = blockIdx.x, tid = threadIdx.x;
    const int base = bsum[u];
    const int end  = (u == NBUCK - 1) ? E : bsum[u + 1];
    const int node0 = u << 8;
    const int rows = min(256, N - node0);

    cnt[tid] = 0;
    __syncthreads();
    for (int e = base + tid; e < end; e += 256)
        atomicAdd(&cnt[pairs[e].y], 1);
    __syncthreads();
    int own = cnt[tid];
    __syncthreads();
    cnt[tid] = own;
    __syncthreads();
    for (int off = 1; off < 256; off <<= 1) {
        int t = (tid >= off) ? cnt[tid - off] : 0;
        __syncthreads();
        cnt[tid] += t;
        __syncthreads();
    }
    const int excl = cnt[tid] - own;
    if (tid < rows) rp[node0 + tid] = base + excl;
    if (tid == 0 && u == nbuckUsed - 1) rp[N] = E;
    cur[tid] = base + excl;
    __syncthreads();
    for (int e = base + tid; e < end; e += 256) {
        int2 p = pairs[e];
        int pos = atomicAdd(&cur[p.y], 1);
        col[pos] = p.x;
    }
}

// ---------------- pre-transform: ybf = bf16(x @ w1a) ----------------
__global__ __launch_bounds__(256)
void pre_kernel(const float* __restrict__ x, const float* __restrict__ wa,
                ushort_t* __restrict__ ybf, int n) {
    __shared__ float s_wa[11 * 64];
    __shared__ float s_row[4][11];
    const int tid = threadIdx.x;
    const int lane = tid & 63;
    const int local = tid >> 6;
    for (int i = tid; i < 11 * 64; i += 256) s_wa[i] = wa[i];
    __syncthreads();
    const int groups = (n + 3) >> 2;
    for (int grp = blockIdx.x; grp < groups; grp += gridDim.x) {
        const int node = grp * 4 + local;
        if (node >= n) continue;
        if (lane < 11) s_row[local][lane] = x[(size_t)node * 11 + lane];
        float acc = 0.f;
        #pragma unroll
        for (int k = 0; k < 11; ++k)
            acc = fmaf(s_row[local][k], s_wa[k * 64 + lane], acc);
        ybf[((size_t)node << 6) + lane] = f2bf(acc);
    }
}

// ------------- aggregate: a[i] = y[i] + sum_{j->i} y[j]  (bf16 gather) -----
// node is wave-uniform (readfirstlane) -> scalar rp/col loads, SALU addresses.
// Tail group pads with index n (zero row), selected by uniform condition.
__global__ __launch_bounds__(256, 8)
void agg_kernel(const ushort_t* __restrict__ ybf, const int* __restrict__ rp,
                const int* __restrict__ col, float* __restrict__ out, int n) {
    int node = __builtin_amdgcn_readfirstlane(
        (int)((blockIdx.x * 256 + threadIdx.x) >> 6));
    if (node >= n) return;
    const int lane = threadIdx.x & 63;
    const int beg = rp[node], end = rp[node + 1];
    float agg = bf2f(ybf[((size_t)node << 6) + lane]);
    int i = beg;
    const int end8 = beg + ((end - beg) & ~7);
    for (; i < end8; i += 8) {
        int c[8];
        float v[8];
        #pragma unroll
        for (int j = 0; j < 8; ++j) c[j] = col[i + j];
        #pragma unroll
        for (int j = 0; j < 8; ++j) v[j] = bf2f(ybf[((size_t)c[j] << 6) + lane]);
        #pragma unroll
        for (int j = 0; j < 8; ++j) agg += v[j];
    }
    if (i < end) {
        int c[8];
        float v[8];
        #pragma unroll
        for (int j = 0; j < 8; ++j) c[j] = (i + j < end) ? col[i + j] : n;
        #pragma unroll
        for (int j = 0; j < 8; ++j) v[j] = bf2f(ybf[((size_t)c[j] << 6) + lane]);
        #pragma unroll
        for (int j = 0; j < 8; ++j) agg += v[j];
    }
    out[((size_t)node << 6) + lane] = agg;
}

// ------------- MLP: t=relu(bn(a+ba)); z=relu(t@wb+bb); y'=bf16(z@wa_next) --
// Weights in VGPRs (lane = output column); t/z broadcast via v_readlane ->
// SGPR FMA operand. No LDS at all.
template<bool LAST>
__global__ __launch_bounds__(256, 3)
void mlp_kernel(const float* __restrict__ a,
                const float* __restrict__ ba,
                const float* __restrict__ gam, const float* __restrict__ bet,
                const float* __restrict__ rm, const float* __restrict__ rv,
                const float* __restrict__ wb, const float* __restrict__ bb,
                const float* __restrict__ wn,
                ushort_t* __restrict__ outbf, float* __restrict__ outf, int n) {
    const int lane = threadIdx.x & 63;

    float wbr[64];
    #pragma unroll
    for (int k = 0; k < 64; ++k) wbr[k] = wb[k * 64 + lane];
    float wnr[LAST ? 1 : 64];
    if (!LAST) {
        #pragma unroll
        for (int k = 0; k < 64; ++k) wnr[k] = wn[k * 64 + lane];
    }

    const float scale = gam[lane] * rsqrtf(rv[lane] + BN_EPS);
    const float shift = bet[lane] - rm[lane] * scale;
    const float ba_l = ba[lane];
    const float bb_l = bb[lane];

    const int wavesTotal = gridDim.x * 4;
    for (int node = blockIdx.x * 4 + (threadIdx.x >> 6); node < n;
         node += wavesTotal) {
        float t = a[((size_t)node << 6) + lane] + ba_l;
        t = fmaf(t, scale, shift);
        t = fmaxf(t, 0.f);

        float acc = bb_l;
        #pragma unroll
        for (int k = 0; k < 64; ++k)
            acc = fmaf(lanebcast(t, k), wbr[k], acc);
        float z = fmaxf(acc, 0.f);

        if (LAST) {
            outf[((size_t)node << 6) + lane] = z;
        } else {
            float acc2 = 0.f;
            #pragma unroll
            for (int k = 0; k < 64; ++k)
                acc2 = fmaf(lanebcast(z, k), wnr[k], acc2);
            outbf[((size_t)node << 6) + lane] = f2bf(acc2);
        }
    }
}

// ---------------- pool: hg[batch[i]] += h[i], batch sorted -----------------
__global__ __launch_bounds__(64)
void pool_kernel(const float* __restrict__ h, const int* __restrict__ batch,
                 float* __restrict__ hg, int n) {
    const int CHUNK = 128;
    const int d = threadIdx.x;
    const int start = blockIdx.x * CHUNK;
    if (start >= n) return;
    const int end = min(start + CHUNK, n);
    float acc = 0.f;
    int cur = batch[start];
    for (int i = start; i < end; ++i) {
        int b = batch[i];
        if (b != cur) {
            atomicAdd(&hg[((size_t)cur << 6) + d], acc);
            acc = 0.f;
            cur = b;
        }
        acc += h[((size_t)i << 6) + d];
    }
    atomicAdd(&hg[((size_t)cur << 6) + d], acc);
}

// ---------------- head: out = relu(hg@lw1+lb1) @ lw2 + lb2 -----------------
__global__ __launch_bounds__(256)
void head_kernel(const float* __restrict__ hg, const float* __restrict__ lw1,
                 const float* __restrict__ lb1, const float* __restrict__ lw2,
                 const float* __restrict__ lb2, float* __restrict__ out,
                 int ngraph) {
    __shared__ float s_w1[64 * 64];
    __shared__ float s_row[4][64];
    const int tid = threadIdx.x;
    const int lane = tid & 63;
    const int local = tid >> 6;
    for (int i = tid; i < 64 * 64; i += 256) s_w1[i] = lw1[i];
    const float b1 = lb1[lane];
    const float w2 = lw2[lane];
    const float b2 = lb2[0];
    __syncthreads();

    const int g = blockIdx.x * 4 + local;
    if (g < ngraph) s_row[local][lane] = hg[((size_t)g << 6) + lane];
    __syncthreads();
    if (g < ngraph) {
        float acc = b1;
        #pragma unroll
        for (int k = 0; k < 64; ++k)
            acc = fmaf(s_row[local][k], s_w1[k * 64 + lane], acc);
        acc = fmaxf(acc, 0.f);
        float r = acc * w2;
        #pragma unroll
        for (int off = 32; off > 0; off >>= 1)
            r += __shfl_down(r, off, 64);
        if (lane == 0) out[g] = r + b2;
    }
}

extern "C" void kernel_launch(void* const* d_in, const int* in_sizes, int n_in,
                              void* d_out, int out_size, void* d_ws, size_t ws_size,
                              hipStream_t stream) {
    const float* x    = (const float*)d_in[0];
    const int* ei     = (const int*)d_in[1];
    const int* batch  = (const int*)d_in[2];
    const int N = in_sizes[0] / 11;
    const int E = in_sizes[1] / 2;
    const int G = out_size;
    const int* src = ei;
    const int* dst = ei + E;

    const float* p[28];
    for (int i = 0; i < 28; ++i) p[i] = (const float*)d_in[3 + i];
    // p[0..7]=L1 {wa,ba,g,be,m,v,wb,bb}, p[8..15]=L2, p[16..23]=L3
    // p[24]=lw1 p[25]=lb1 p[26]=lw2 p[27]=lb2

    ushort_t* ybf = (ushort_t*)d_ws;                    // [(N+1),64] bf16
    float* aggb  = (float*)(ybf + ((size_t)N + 1) * 64);// [N,64]
    float* h3    = aggb + (size_t)N * 64;               // [N,64]
    int*   ghist = (int*)(h3 + (size_t)N * 64);         // [NBUCK*NBLK]
    int*   bsum  = ghist + NBUCK * NBLK;                // [512]
    int*   rp    = bsum + 512;                          // [N+1]
    int*   col   = rp + N + 1;                          // [E]
    int2*  pairs = (int2*)(col + E);                    // [E]
    float* hg    = (float*)(pairs + E);                 // [G,64]

    const int chunk     = (E + NBLK - 1) / NBLK;
    const int nscan     = NBUCK * NBLK;
    const int nbScanB   = nscan / 256;
    const int nbuckUsed = (N + 255) >> 8;
    const int nbNode    = (N * 64 + 255) / 256;         // wave = node

    // zero row (index N) for tail padding in agg
    hipMemsetAsync(ybf + (size_t)N * 64, 0, 64 * sizeof(ushort_t), stream);

    // ---- CSR build ----
    bin_hist_kernel<<<NBLK, 256, 0, stream>>>(dst, ghist, E, chunk);
    scan_block_g<<<nbScanB, 256, 0, stream>>>(ghist, bsum, nscan);
    scan_top_kernel<<<1, 512, 0, stream>>>(bsum, nbScanB);
    bin_fill_kernel<<<NBLK, 256, 0, stream>>>(src, dst, ghist, bsum, pairs, E, chunk);
    csr_sort_kernel<<<nbuckUsed, 256, 0, stream>>>(pairs, bsum, col, rp, N, E, nbuckUsed);

    // ---- pre-transform ybf = bf16(x @ w1a) ----
    pre_kernel<<<2048, 256, 0, stream>>>(x, p[0], ybf, N);

    // ---- layer 1 ----
    agg_kernel<<<nbNode, 256, 0, stream>>>(ybf, rp, col, aggb, N);
    mlp_kernel<false><<<768, 256, 0, stream>>>(aggb, p[1], p[2], p[3], p[4],
        p[5], p[6], p[7], p[8], ybf, nullptr, N);
    // ---- layer 2 ----
    agg_kernel<<<nbNode, 256, 0, stream>>>(ybf, rp, col, aggb, N);
    mlp_kernel<false><<<768, 256, 0, stream>>>(aggb, p[9], p[10], p[11], p[12],
        p[13], p[14], p[15], p[16], ybf, nullptr, N);
    // ---- layer 3 ----
    agg_kernel<<<nbNode, 256, 0, stream>>>(ybf, rp, col, aggb, N);
    mlp_kernel<true><<<768, 256, 0, stream>>>(aggb, p[17], p[18], p[19], p[20],
        p[21], p[22], p[23], nullptr, nullptr, h3, N);

    // ---- pool ----
    hipMemsetAsync(hg, 0, (size_t)G * 64 * sizeof(float), stream);
    pool_kernel<<<(N + 127) / 128, 64, 0, stream>>>(h3, batch, hg, N);

    // ---- head ----
    head_kernel<<<(G + 3) / 4, 256, 0, stream>>>(hg,
        p[24], p[25], p[26], p[27], (float*)d_out, G);
}

// Round 8
// 241.042 us; speedup vs baseline: 7.6410x; 1.4509x over previous
//
#include <hip/hip_runtime.h>

// GIN forward: transformed-space linearity (y = h@wa; agg@wa = y_self + sum y_nbr)
// y table bf16, CSR via bucket binning + counting sort, scalarized wave-per-node
// gather agg, MFMA MLP (16 nodes/wave, weights as B-fragments in VGPRs),
// pool, head. N=100000, E=1200000, DIM=64, G=1000, IN=11.

#define BN_EPS 1e-5f
#define NBUCK 512
#define NBLK  256

typedef unsigned short ushort_t;
typedef __attribute__((ext_vector_type(8))) short short8v;   // 8 bf16 (4 VGPRs)
typedef __attribute__((ext_vector_type(4))) float float4v;   // 4 fp32 acc

__device__ __forceinline__ ushort_t f2bf(float x) {
    unsigned u = __float_as_uint(x);
    unsigned r = (u + 0x7FFF + ((u >> 16) & 1)) >> 16;   // RNE
    return (ushort_t)r;
}
__device__ __forceinline__ float bf2f(ushort_t b) {
    return __uint_as_float((unsigned)b << 16);
}

// ---------------- binning: per-block histogram (bucket-major layout) -------
__global__ __launch_bounds__(256)
void bin_hist_kernel(const int* __restrict__ dst, int* __restrict__ ghist,
                     int E, int chunk) {
    __shared__ int h[NBUCK];
    const int tid = threadIdx.x, blk = blockIdx.x;
    for (int u = tid; u < NBUCK; u += 256) h[u] = 0;
    __syncthreads();
    const int e0 = blk * chunk, e1 = min(E, e0 + chunk);
    for (int e = e0 + tid; e < e1; e += 256)
        atomicAdd(&h[dst[e] >> 8], 1);
    __syncthreads();
    for (int u = tid; u < NBUCK; u += 256)
        ghist[u * NBLK + blk] = h[u];
}

// ---------------- hierarchical exclusive scan ------------------------------
__global__ __launch_bounds__(256)
void scan_block_g(int* __restrict__ a, int* __restrict__ bsum, int n) {
    __shared__ int s[256];
    int i = blockIdx.x * 256 + threadIdx.x;
    int v = (i < n) ? a[i] : 0;
    s[threadIdx.x] = v;
    __syncthreads();
    for (int off = 1; off < 256; off <<= 1) {
        int t = (threadIdx.x >= off) ? s[threadIdx.x - off] : 0;
        __syncthreads();
        s[threadIdx.x] += t;
        __syncthreads();
    }
    if (i < n) a[i] = s[threadIdx.x] - v;
    if (threadIdx.x == 255) bsum[blockIdx.x] = s[255];
}

__global__ __launch_bounds__(512)
void scan_top_kernel(int* bsum, int nb) {
    __shared__ int s[512];
    int v = (threadIdx.x < nb) ? bsum[threadIdx.x] : 0;
    s[threadIdx.x] = v;
    __syncthreads();
    for (int off = 1; off < 512; off <<= 1) {
        int t = (threadIdx.x >= off) ? s[threadIdx.x - off] : 0;
        __syncthreads();
        s[threadIdx.x] += t;
        __syncthreads();
    }
    if (threadIdx.x < nb) bsum[threadIdx.x] = s[threadIdx.x] - v;
}

// ------- bin fill: block-local LDS cursors -> clustered pair writes --------
__global__ __launch_bounds__(256)
void bin_fill_kernel(const int* __restrict__ src, const int* __restrict__ dst,
                     const int* __restrict__ ghist, const int* __restrict__ bsum,
                     int2* __restrict__ pairs, int E, int chunk) {
    __shared__ int cur[NBUCK];
    const int tid = threadIdx.x, blk = blockIdx.x;
    for (int u = tid; u < NBUCK; u += 256)
        cur[u] = ghist[u * NBLK + blk] + bsum[u];
    __syncthreads();
    const int e0 = blk * chunk, e1 = min(E, e0 + chunk);
    for (int e = e0 + tid; e < e1; e += 256) {
        int d = dst[e];
        int pos = atomicAdd(&cur[d >> 8], 1);
        pairs[pos] = make_int2(src[e], d & 255);
    }
}

// ------- per-bucket counting sort -> per-node CSR (col, rp) ----------------
__global__ __launch_bounds__(256)
void csr_sort_kernel(const int2* __restrict__ pairs, const int* __restrict__ bsum,
                     int* __restrict__ col, int* __restrict__ rp,
                     int N, int E, int nbuckUsed) {
    __shared__ int cnt[256];
    __shared__ int cur[256];
    const int u = blockIdx.x, tid = threadIdx.x;
    const int base = bsum[u];
    const int end  = (u == NBUCK - 1) ? E : bsum[u + 1];
    const int node0 = u << 8;
    const int rows = min(256, N - node0);

    cnt[tid] = 0;
    __syncthreads();
    for (int e = base + tid; e < end; e += 256)
        atomicAdd(&cnt[pairs[e].y], 1);
    __syncthreads();
    int own = cnt[tid];
    __syncthreads();
    cnt[tid] = own;
    __syncthreads();
    for (int off = 1; off < 256; off <<= 1) {
        int t = (tid >= off) ? cnt[tid - off] : 0;
        __syncthreads();
        cnt[tid] += t;
        __syncthreads();
    }
    const int excl = cnt[tid] - own;
    if (tid < rows) rp[node0 + tid] = base + excl;
    if (tid == 0 && u == nbuckUsed - 1) rp[N] = E;
    cur[tid] = base + excl;
    __syncthreads();
    for (int e = base + tid; e < end; e += 256) {
        int2 p = pairs[e];
        int pos = atomicAdd(&cur[p.y], 1);
        col[pos] = p.x;
    }
}

// ---------------- pre-transform: ybf = bf16(x @ w1a) ----------------
__global__ __launch_bounds__(256)
void pre_kernel(const float* __restrict__ x, const float* __restrict__ wa,
                ushort_t* __restrict__ ybf, int n) {
    __shared__ float s_wa[11 * 64];
    __shared__ float s_row[4][11];
    const int tid = threadIdx.x;
    const int lane = tid & 63;
    const int local = tid >> 6;
    for (int i = tid; i < 11 * 64; i += 256) s_wa[i] = wa[i];
    __syncthreads();
    const int groups = (n + 3) >> 2;
    for (int grp = blockIdx.x; grp < groups; grp += gridDim.x) {
        const int node = grp * 4 + local;
        if (node >= n) continue;
        if (lane < 11) s_row[local][lane] = x[(size_t)node * 11 + lane];
        float acc = 0.f;
        #pragma unroll
        for (int k = 0; k < 11; ++k)
            acc = fmaf(s_row[local][k], s_wa[k * 64 + lane], acc);
        ybf[((size_t)node << 6) + lane] = f2bf(acc);
    }
}

// ------------- aggregate: a[i] = y[i] + sum_{j->i} y[j]  (bf16 gather) -----
__global__ __launch_bounds__(256, 8)
void agg_kernel(const ushort_t* __restrict__ ybf, const int* __restrict__ rp,
                const int* __restrict__ col, float* __restrict__ out, int n) {
    int node = __builtin_amdgcn_readfirstlane(
        (int)((blockIdx.x * 256 + threadIdx.x) >> 6));
    if (node >= n) return;
    const int lane = threadIdx.x & 63;
    const int beg = rp[node], end = rp[node + 1];
    float agg = bf2f(ybf[((size_t)node << 6) + lane]);
    int i = beg;
    const int end8 = beg + ((end - beg) & ~7);
    for (; i < end8; i += 8) {
        int c[8];
        float v[8];
        #pragma unroll
        for (int j = 0; j < 8; ++j) c[j] = col[i + j];
        #pragma unroll
        for (int j = 0; j < 8; ++j) v[j] = bf2f(ybf[((size_t)c[j] << 6) + lane]);
        #pragma unroll
        for (int j = 0; j < 8; ++j) agg += v[j];
    }
    if (i < end) {
        int c[8];
        float v[8];
        #pragma unroll
        for (int j = 0; j < 8; ++j) c[j] = (i + j < end) ? col[i + j] : n;
        #pragma unroll
        for (int j = 0; j < 8; ++j) v[j] = bf2f(ybf[((size_t)c[j] << 6) + lane]);
        #pragma unroll
        for (int j = 0; j < 8; ++j) agg += v[j];
    }
    out[((size_t)node << 6) + lane] = agg;
}

// ------------- MFMA MLP: t=relu(bn(a+ba)); z=relu(t@wb+bb); y'=z@wn -------
// Wave = 16 nodes. t built directly in A-fragment layout (lane: row=lane&15,
// k=(lane>>4)*8+j per k-tile). Weights as B-fragments in VGPRs. z re-layout
// C->A via wave-private LDS tile. C/D layout: col=lane&15, row=(lane>>4)*4+reg.
template<bool LAST>
__global__ __launch_bounds__(256, 2)
void mlp_mfma_kernel(const float* __restrict__ a,     // [n,64] agg fp32
                     const float* __restrict__ ba,
                     const float* __restrict__ gam, const float* __restrict__ bet,
                     const float* __restrict__ rm, const float* __restrict__ rv,
                     const float* __restrict__ wb, const float* __restrict__ bb,
                     const float* __restrict__ wn,
                     ushort_t* __restrict__ outbf, float* __restrict__ outf,
                     int n) {
    __shared__ ushort_t zt[4][16][72];     // per-wave z tile, 144B stride (16B aligned)
    __shared__ float s_sc[64], s_sh[64];

    const int tid  = threadIdx.x;
    const int lane = tid & 63;
    const int w    = tid >> 6;
    const int half = lane >> 4;    // k-group / row-group
    const int sub  = lane & 15;    // row (A) / col (C)

    if (tid < 64) {
        float s = gam[tid] * rsqrtf(rv[tid] + BN_EPS);
        s_sc[tid] = s;
        s_sh[tid] = bet[tid] - rm[tid] * s + ba[tid] * s;  // fold GIN lin-a bias
    }

    // B-fragments: frag[kk][nt][j] = w[kk*32 + half*8 + j][nt*16 + sub]
    short8v wbf[2][4];
    #pragma unroll
    for (int kk = 0; kk < 2; ++kk)
        #pragma unroll
        for (int nt = 0; nt < 4; ++nt) {
            short8v f;
            #pragma unroll
            for (int j = 0; j < 8; ++j)
                f[j] = (short)f2bf(wb[(kk * 32 + half * 8 + j) * 64 + nt * 16 + sub]);
            wbf[kk][nt] = f;
        }
    short8v wnf[LAST ? 1 : 2][4];
    if (!LAST) {
        #pragma unroll
        for (int kk = 0; kk < 2; ++kk)
            #pragma unroll
            for (int nt = 0; nt < 4; ++nt) {
                short8v f;
                #pragma unroll
                for (int j = 0; j < 8; ++j)
                    f[j] = (short)f2bf(wn[(kk * 32 + half * 8 + j) * 64 + nt * 16 + sub]);
                wnf[kk][nt] = f;
            }
    }
    float bbr[4];
    #pragma unroll
    for (int nt = 0; nt < 4; ++nt) bbr[nt] = bb[nt * 16 + sub];
    __syncthreads();

    const int ngroups = (n + 15) >> 4;
    const int stride = gridDim.x * 4;
    for (int group = blockIdx.x * 4 + w; group < ngroups; group += stride) {
        const int node0 = group << 4;
        int mrow = node0 + sub;
        if (mrow >= n) mrow = n - 1;              // stores are guarded

        // ---- A fragments of t (BN+ReLU applied in fp32, cast bf16) ----
        short8v at[2];
        #pragma unroll
        for (int kk = 0; kk < 2; ++kk) {
            const float4* pa =
                (const float4*)&a[((size_t)mrow << 6) + kk * 32 + half * 8];
            float4 v0 = pa[0], v1 = pa[1];
            const float4* psc = (const float4*)&s_sc[kk * 32 + half * 8];
            const float4* psh = (const float4*)&s_sh[kk * 32 + half * 8];
            float4 c0 = psc[0], c1 = psc[1];
            float4 h0 = psh[0], h1 = psh[1];
            short8v f;
            f[0] = (short)f2bf(fmaxf(fmaf(v0.x, c0.x, h0.x), 0.f));
            f[1] = (short)f2bf(fmaxf(fmaf(v0.y, c0.y, h0.y), 0.f));
            f[2] = (short)f2bf(fmaxf(fmaf(v0.z, c0.z, h0.z), 0.f));
            f[3] = (short)f2bf(fmaxf(fmaf(v0.w, c0.w, h0.w), 0.f));
            f[4] = (short)f2bf(fmaxf(fmaf(v1.x, c1.x, h1.x), 0.f));
            f[5] = (short)f2bf(fmaxf(fmaf(v1.y, c1.y, h1.y), 0.f));
            f[6] = (short)f2bf(fmaxf(fmaf(v1.z, c1.z, h1.z), 0.f));
            f[7] = (short)f2bf(fmaxf(fmaf(v1.w, c1.w, h1.w), 0.f));
            at[kk] = f;
        }

        // ---- GEMM1: z = relu(t @ wb + bb) ----
        float4v accz[4];
        #pragma unroll
        for (int nt = 0; nt < 4; ++nt) {
            float4v c = {0.f, 0.f, 0.f, 0.f};
            c = __builtin_amdgcn_mfma_f32_16x16x32_bf16(at[0], wbf[0][nt], c, 0, 0, 0);
            c = __builtin_amdgcn_mfma_f32_16x16x32_bf16(at[1], wbf[1][nt], c, 0, 0, 0);
            accz[nt] = c;
        }

        if (LAST) {
            #pragma unroll
            for (int nt = 0; nt < 4; ++nt)
                #pragma unroll
                for (int r = 0; r < 4; ++r) {
                    int m = node0 + half * 4 + r;
                    if (m < n)
                        outf[((size_t)m << 6) + nt * 16 + sub] =
                            fmaxf(accz[nt][r] + bbr[nt], 0.f);
                }
        } else {
            // z -> bf16 -> LDS (C layout), read back in A layout
            #pragma unroll
            for (int nt = 0; nt < 4; ++nt)
                #pragma unroll
                for (int r = 0; r < 4; ++r)
                    zt[w][half * 4 + r][nt * 16 + sub] =
                        f2bf(fmaxf(accz[nt][r] + bbr[nt], 0.f));
            asm volatile("s_waitcnt lgkmcnt(0)" ::: "memory");
            short8v az[2];
            #pragma unroll
            for (int kk = 0; kk < 2; ++kk)
                az[kk] = *(const short8v*)&zt[w][sub][kk * 32 + half * 8];

            // ---- GEMM2: y' = z @ wn, store bf16 ----
            #pragma unroll
            for (int nt = 0; nt < 4; ++nt) {
                float4v c = {0.f, 0.f, 0.f, 0.f};
                c = __builtin_amdgcn_mfma_f32_16x16x32_bf16(az[0], wnf[0][nt], c, 0, 0, 0);
                c = __builtin_amdgcn_mfma_f32_16x16x32_bf16(az[1], wnf[1][nt], c, 0, 0, 0);
                #pragma unroll
                for (int r = 0; r < 4; ++r) {
                    int m = node0 + half * 4 + r;
                    if (m < n)
                        outbf[((size_t)m << 6) + nt * 16 + sub] = f2bf(c[r]);
                }
            }
        }
    }
}

// ---------------- pool: hg[batch[i]] += h[i], batch sorted -----------------
__global__ __launch_bounds__(64)
void pool_kernel(const float* __restrict__ h, const int* __restrict__ batch,
                 float* __restrict__ hg, int n) {
    const int CHUNK = 128;
    const int d = threadIdx.x;
    const int start = blockIdx.x * CHUNK;
    if (start >= n) return;
    const int end = min(start + CHUNK, n);
    float acc = 0.f;
    int cur = batch[start];
    for (int i = start; i < end; ++i) {
        int b = batch[i];
        if (b != cur) {
            atomicAdd(&hg[((size_t)cur << 6) + d], acc);
            acc = 0.f;
            cur = b;
        }
        acc += h[((size_t)i << 6) + d];
    }
    atomicAdd(&hg[((size_t)cur << 6) + d], acc);
}

// ---------------- head: out = relu(hg@lw1+lb1) @ lw2 + lb2 -----------------
__global__ __launch_bounds__(256)
void head_kernel(const float* __restrict__ hg, const float* __restrict__ lw1,
                 const float* __restrict__ lb1, const float* __restrict__ lw2,
                 const float* __restrict__ lb2, float* __restrict__ out,
                 int ngraph) {
    __shared__ float s_w1[64 * 64];
    __shared__ float s_row[4][64];
    const int tid = threadIdx.x;
    const int lane = tid & 63;
    const int local = tid >> 6;
    for (int i = tid; i < 64 * 64; i += 256) s_w1[i] = lw1[i];
    const float b1 = lb1[lane];
    const float w2 = lw2[lane];
    const float b2 = lb2[0];
    __syncthreads();

    const int g = blockIdx.x * 4 + local;
    if (g < ngraph) s_row[local][lane] = hg[((size_t)g << 6) + lane];
    __syncthreads();
    if (g < ngraph) {
        float acc = b1;
        #pragma unroll
        for (int k = 0; k < 64; ++k)
            acc = fmaf(s_row[local][k], s_w1[k * 64 + lane], acc);
        acc = fmaxf(acc, 0.f);
        float r = acc * w2;
        #pragma unroll
        for (int off = 32; off > 0; off >>= 1)
            r += __shfl_down(r, off, 64);
        if (lane == 0) out[g] = r + b2;
    }
}

extern "C" void kernel_launch(void* const* d_in, const int* in_sizes, int n_in,
                              void* d_out, int out_size, void* d_ws, size_t ws_size,
                              hipStream_t stream) {
    const float* x    = (const float*)d_in[0];
    const int* ei     = (const int*)d_in[1];
    const int* batch  = (const int*)d_in[2];
    const int N = in_sizes[0] / 11;
    const int E = in_sizes[1] / 2;
    const int G = out_size;
    const int* src = ei;
    const int* dst = ei + E;

    const float* p[28];
    for (int i = 0; i < 28; ++i) p[i] = (const float*)d_in[3 + i];
    // p[0..7]=L1 {wa,ba,g,be,m,v,wb,bb}, p[8..15]=L2, p[16..23]=L3
    // p[24]=lw1 p[25]=lb1 p[26]=lw2 p[27]=lb2

    ushort_t* ybf = (ushort_t*)d_ws;                    // [(N+1),64] bf16
    float* aggb  = (float*)(ybf + ((size_t)N + 1) * 64);// [N,64]
    float* h3    = aggb + (size_t)N * 64;               // [N,64]
    int*   ghist = (int*)(h3 + (size_t)N * 64);         // [NBUCK*NBLK]
    int*   bsum  = ghist + NBUCK * NBLK;                // [512]
    int*   rp    = bsum + 512;                          // [N+1]
    int*   col   = rp + N + 1;                          // [E]
    int2*  pairs = (int2*)(col + E);                    // [E]
    float* hg    = (float*)(pairs + E);                 // [G,64]

    const int chunk     = (E + NBLK - 1) / NBLK;
    const int nscan     = NBUCK * NBLK;
    const int nbScanB   = nscan / 256;
    const int nbuckUsed = (N + 255) >> 8;
    const int nbNode    = (N * 64 + 255) / 256;         // wave = node

    // zero row (index N) for tail padding in agg
    hipMemsetAsync(ybf + (size_t)N * 64, 0, 64 * sizeof(ushort_t), stream);

    // ---- CSR build ----
    bin_hist_kernel<<<NBLK, 256, 0, stream>>>(dst, ghist, E, chunk);
    scan_block_g<<<nbScanB, 256, 0, stream>>>(ghist, bsum, nscan);
    scan_top_kernel<<<1, 512, 0, stream>>>(bsum, nbScanB);
    bin_fill_kernel<<<NBLK, 256, 0, stream>>>(src, dst, ghist, bsum, pairs, E, chunk);
    csr_sort_kernel<<<nbuckUsed, 256, 0, stream>>>(pairs, bsum, col, rp, N, E, nbuckUsed);

    // ---- pre-transform ybf = bf16(x @ w1a) ----
    pre_kernel<<<2048, 256, 0, stream>>>(x, p[0], ybf, N);

    // ---- layer 1 ----
    agg_kernel<<<nbNode, 256, 0, stream>>>(ybf, rp, col, aggb, N);
    mlp_mfma_kernel<false><<<512, 256, 0, stream>>>(aggb, p[1], p[2], p[3], p[4],
        p[5], p[6], p[7], p[8], ybf, nullptr, N);
    // ---- layer 2 ----
    agg_kernel<<<nbNode, 256, 0, stream>>>(ybf, rp, col, aggb, N);
    mlp_mfma_kernel<false><<<512, 256, 0, stream>>>(aggb, p[9], p[10], p[11], p[12],
        p[13], p[14], p[15], p[16], ybf, nullptr, N);
    // ---- layer 3 ----
    agg_kernel<<<nbNode, 256, 0, stream>>>(ybf, rp, col, aggb, N);
    mlp_mfma_kernel<true><<<512, 256, 0, stream>>>(aggb, p[17], p[18], p[19], p[20],
        p[21], p[22], p[23], nullptr, nullptr, h3, N);

    // ---- pool ----
    hipMemsetAsync(hg, 0, (size_t)G * 64 * sizeof(float), stream);
    pool_kernel<<<(N + 127) / 128, 64, 0, stream>>>(h3, batch, hg, N);

    // ---- head ----
    head_kernel<<<(G + 3) / 4, 256, 0, stream>>>(hg,
        p[24], p[25], p[26], p[27], (float*)d_out, G);
}